// Round 4
// baseline (100.851 us; speedup 1.0000x reference)
//
#include <hip/hip_runtime.h>
#include <hip/hip_fp16.h>

#define P_PAD 208

typedef __attribute__((ext_vector_type(8))) short f16x8;
typedef __attribute__((ext_vector_type(4))) float f32x4;

__device__ __forceinline__ unsigned short f2h(float x) {
    __half h = __float2half(x);           // RNE f32 -> f16
    unsigned short u;
    __builtin_memcpy(&u, &h, 2);
    return u;
}

// ---------------- kernel 1: L2-normalize rows, f32 -> f16, pad to 208 rows ----
__global__ __launch_bounds__(256) void norm_kernel(
    const float* __restrict__ feats, const float* __restrict__ nfeats,
    unsigned short* __restrict__ fH, unsigned short* __restrict__ nfH)
{
    int row  = blockIdx.x * 4 + (threadIdx.x >> 6);   // one wave per padded row
    int lane = threadIdx.x & 63;
    const int ROWS_F = 32 * P_PAD;
    const float* src;
    unsigned short* dst;
    int r;
    if (row < ROWS_F) {
        int a = row / P_PAD; r = row % P_PAD;
        src = feats + ((size_t)a * 196 + r) * 128;
        dst = fH + (size_t)row * 128;
    } else {
        int row2 = row - ROWS_F;
        int b = row2 / P_PAD; r = row2 % P_PAD;
        src = nfeats + ((size_t)b * 196 + r) * 128;
        dst = nfH + (size_t)row2 * 128;
    }
    if (r < 196) {
        float2 v = *(const float2*)(src + lane * 2);
        float ss = v.x * v.x + v.y * v.y;
        #pragma unroll
        for (int m = 1; m < 64; m <<= 1) ss += __shfl_xor(ss, m, 64);
        float rn = rsqrtf(ss);
        ushort2 o; o.x = f2h(v.x * rn); o.y = f2h(v.y * rn);
        *(ushort2*)(dst + lane * 2) = o;
    } else {
        *(unsigned int*)(dst + lane * 2) = 0u;   // zero pad rows
    }
}

// ---------------- kernel 2: per (a,b): simmax over q, dist, mask, max over p ----
// One MFMA-tile compute over a 16-col q-tile held in BUF; MASKED only for tile 12.
#define COMPUTE(BUF, MASKED)                                                   \
  {                                                                            \
    f32x4 acc[4];                                                              \
    _Pragma("unroll")                                                          \
    for (int i = 0; i < 4; ++i) acc[i] = (f32x4){0.f, 0.f, 0.f, 0.f};          \
    _Pragma("unroll")                                                          \
    for (int ks = 0; ks < 4; ++ks) {                                           \
      _Pragma("unroll")                                                        \
      for (int i = 0; i < 4; ++i) {                                            \
        if (i < 3 || wave == 0)                                                \
          asm("v_mfma_f32_16x16x32_f16 %0, %1, %2, %0"                         \
              : "+v"(acc[i]) : "v"(afr[i][ks]), "v"(BUF[ks]));                 \
      }                                                                        \
    }                                                                          \
    asm volatile("s_nop 7\n\ts_nop 7");                                        \
    _Pragma("unroll")                                                          \
    for (int i = 0; i < 4; ++i) {                                              \
      if (i < 3 || wave == 0) {                                                \
        _Pragma("unroll")                                                      \
        for (int r = 0; r < 4; ++r) {                                          \
          float v = acc[i][r];                                                 \
          if (MASKED) v = (lr < 4) ? v : -3.0f;                                \
          runmax[i][r] = fmaxf(runmax[i][r], v);                               \
        }                                                                      \
      }                                                                        \
    }                                                                          \
  }

__global__ __launch_bounds__(256, 3) void simmax_kernel(
    const unsigned short* __restrict__ fH, const unsigned short* __restrict__ nfH,
    const float* __restrict__ mask, float* __restrict__ sp, float* __restrict__ scores)
{
    int blk = blockIdx.x;
    int b = blk >> 5, a = blk & 31;      // b-major: 32 consecutive blocks share b -> L2-hot nf[b]
    int tid = threadIdx.x, wave = tid >> 6, lane = tid & 63;
    int lr = lane & 15, lg = lane >> 4;

    __shared__ unsigned smax_u;
    if (tid == 0) smax_u = 0u;
    __syncthreads();

    const unsigned short* fbase = fH  + (size_t)a * P_PAD * 128;
    const unsigned short* nbase = nfH + (size_t)b * P_PAD * 128;

    // A fragments, register-resident for the whole kernel. Tiles: mt = wave + 4*i.
    // per-lane k-mapping: k = 32*ks + 8*lg + j (same for B -> layout-convention-invariant)
    f16x8 afr[4][4];
    #pragma unroll
    for (int i = 0; i < 4; ++i) {
        if (i < 3 || wave == 0) {                  // only wave 0 owns tile 12
            int mt = wave + 4 * i;
            const unsigned short* rp = fbase + (size_t)(mt * 16 + lr) * 128 + lg * 8;
            #pragma unroll
            for (int ks = 0; ks < 4; ++ks)
                afr[i][ks] = *(const f16x8*)(rp + ks * 32);
        }
    }
    // Pin: make each fragment's def an opaque volatile asm so the compiler can
    // neither rematerialize the load inside the loop nor sink it. Forces true
    // register residency (the round-3 VGPR=80 showed remat-by-reload).
    #pragma unroll
    for (int i = 0; i < 4; ++i) {
        if (i < 3 || wave == 0) {
            #pragma unroll
            for (int ks = 0; ks < 4; ++ks)
                asm volatile("" : "+v"(afr[i][ks]));
        }
    }

    float runmax[4][4];
    #pragma unroll
    for (int i = 0; i < 4; ++i)
        #pragma unroll
        for (int r = 0; r < 4; ++r) runmax[i][r] = -3.0f;

    const unsigned short* qbase = nbase + (size_t)lr * 128 + lg * 8;
    f16x8 bufA[4], bufB[4];
    #pragma unroll
    for (int ks = 0; ks < 4; ++ks) bufA[ks] = *(const f16x8*)(qbase + ks * 32);

    // tiles 0..11 are fully valid (q < 192 < 196); only tile 12 needs masking
    for (int qt = 0; qt < 12; qt += 2) {
        const unsigned short* q1 = qbase + (size_t)(qt + 1) * 16 * 128;
        #pragma unroll
        for (int ks = 0; ks < 4; ++ks) bufB[ks] = *(const f16x8*)(q1 + ks * 32);
        COMPUTE(bufA, false);
        const unsigned short* q2 = qbase + (size_t)(qt + 2) * 16 * 128;
        #pragma unroll
        for (int ks = 0; ks < 4; ++ks) bufA[ks] = *(const f16x8*)(q2 + ks * 32);
        COMPUTE(bufB, false);
    }
    COMPUTE(bufA, true);   // tile 12: q = 192..207, valid iff lr < 4

    // reduce max across the 16 q-columns (lane bits 0..3), then write
    float blockmax = 0.0f;
    #pragma unroll
    for (int i = 0; i < 4; ++i) {
        if (i < 3 || wave == 0) {
            int mt = wave + 4 * i;
            #pragma unroll
            for (int r = 0; r < 4; ++r) {
                float m = runmax[i][r];
                m = fmaxf(m, __shfl_xor(m, 1, 64));
                m = fmaxf(m, __shfl_xor(m, 2, 64));
                m = fmaxf(m, __shfl_xor(m, 4, 64));
                m = fmaxf(m, __shfl_xor(m, 8, 64));
                if (lr == 0) {
                    int p = mt * 16 + lg * 4 + r;     // C/D layout: row = 4*(lane>>4)+reg
                    if (p < 196) {
                        float d = 0.5f * sqrtf(fmaxf(2.0f - 2.0f * m, 0.0f)) * mask[a * 196 + p];
                        sp[((size_t)a * 196 + p) * 64 + b] = d;   // [a][p][b] for coalesced mean
                        blockmax = fmaxf(blockmax, d);
                    }
                }
            }
        }
    }
    atomicMax(&smax_u, __float_as_uint(blockmax));   // all values >= 0
    __syncthreads();
    if (tid == 0) scores[a * 64 + b] = __uint_as_float(smax_u);
}

// ---------------- kernel 3: patch mean over b + scores mean ----
__global__ __launch_bounds__(256) void patchmean_kernel(
    const float* __restrict__ sp, const float* __restrict__ scores,
    float* __restrict__ patch, float* __restrict__ out)
{
    int a = blockIdx.x, tid = threadIdx.x;
    if (tid < 196) {
        const f32x4* v = (const f32x4*)(sp + ((size_t)a * 196 + tid) * 64);
        float s = 0.0f;
        #pragma unroll
        for (int j = 0; j < 16; ++j) { f32x4 x = v[j]; s += x[0] + x[1] + x[2] + x[3]; }
        patch[a * 196 + tid] = s * (1.0f / 64.0f);
    }
    if (tid >= 192) {                      // wave 3: scores mean
        int l = tid - 192;
        float s = scores[a * 64 + l];
        #pragma unroll
        for (int m = 1; m < 64; m <<= 1) s += __shfl_xor(s, m, 64);
        if (l == 0) out[a] = s * (1.0f / 64.0f);
    }
}

// ---------------- kernel 4: bilinear 14x14 -> 224x224, 8-row bands ----
__global__ __launch_bounds__(256) void upsample_kernel(
    const float* __restrict__ patch, float* __restrict__ out)
{
    int bid = blockIdx.x;
    int a = bid / 28, band = bid % 28;
    __shared__ float pt[196];
    if (threadIdx.x < 196) pt[threadIdx.x] = patch[a * 196 + threadIdx.x];
    __syncthreads();

    float* op = out + 32 + (size_t)a * 50176 + band * 8 * 224;
    for (int t = threadIdx.x; t < 8 * 224; t += 256) {
        int h = band * 8 + (t / 224), w = t % 224;
        float sh = fmaxf((h + 0.5f) * 0.0625f - 0.5f, 0.0f);   // 14/224 = 1/16
        float sw = fmaxf((w + 0.5f) * 0.0625f - 0.5f, 0.0f);
        int h0 = (int)sh, w0 = (int)sw;
        int h1 = min(h0 + 1, 13), w1 = min(w0 + 1, 13);
        float fh = sh - (float)h0, fw = sw - (float)w0;
        float v00 = pt[h0 * 14 + w0], v01 = pt[h0 * 14 + w1];
        float v10 = pt[h1 * 14 + w0], v11 = pt[h1 * 14 + w1];
        op[t] = (1.0f - fh) * ((1.0f - fw) * v00 + fw * v01)
              +         fh  * ((1.0f - fw) * v10 + fw * v11);
    }
}

extern "C" void kernel_launch(void* const* d_in, const int* in_sizes, int n_in,
                              void* d_out, int out_size, void* d_ws, size_t ws_size,
                              hipStream_t stream) {
    const float* feats  = (const float*)d_in[0];   // [32,196,128]
    const float* nfeats = (const float*)d_in[1];   // [64,196,128]
    const float* mask   = (const float*)d_in[2];   // [32,196]
    float* out = (float*)d_out;                    // 32 + 32*224*224

    char* w = (char*)d_ws;
    unsigned short* fH  = (unsigned short*)(w);            // 32*208*128 f16 = 1,703,936 B
    unsigned short* nfH = (unsigned short*)(w + 1703936);  // 64*208*128 f16 = 3,407,872 B
    float* sp     = (float*)(w + 5111808);                 // 32*196*64 f32  = 1,605,632 B
    float* scores = (float*)(w + 6717440);                 // 2048 f32
    float* patch  = (float*)(w + 6725632);                 // 32*196 f32

    norm_kernel<<<4992, 256, 0, stream>>>(feats, nfeats, fH, nfH);
    simmax_kernel<<<2048, 256, 0, stream>>>(fH, nfH, mask, sp, scores);
    patchmean_kernel<<<32, 256, 0, stream>>>(sp, scores, patch, out);
    upsample_kernel<<<896, 256, 0, stream>>>(patch, out);
}

// Round 5
// 87.250 us; speedup vs baseline: 1.1559x; 1.1559x over previous
//
#include <hip/hip_runtime.h>
#include <hip/hip_fp16.h>

#define P_PAD 208

typedef __attribute__((ext_vector_type(8))) short f16x8;
typedef __attribute__((ext_vector_type(4))) float f32x4;

__device__ __forceinline__ unsigned short f2h(float x) {
    __half h = __float2half(x);           // RNE f32 -> f16
    unsigned short u;
    __builtin_memcpy(&u, &h, 2);
    return u;
}

// ---------------- kernel 1: L2-normalize rows, f32 -> f16, pad to 208 rows ----
__global__ __launch_bounds__(256) void norm_kernel(
    const float* __restrict__ feats, const float* __restrict__ nfeats,
    unsigned short* __restrict__ fH, unsigned short* __restrict__ nfH)
{
    int row  = blockIdx.x * 4 + (threadIdx.x >> 6);   // one wave per padded row
    int lane = threadIdx.x & 63;
    const int ROWS_F = 32 * P_PAD;
    const float* src;
    unsigned short* dst;
    int r;
    if (row < ROWS_F) {
        int a = row / P_PAD; r = row % P_PAD;
        src = feats + ((size_t)a * 196 + r) * 128;
        dst = fH + (size_t)row * 128;
    } else {
        int row2 = row - ROWS_F;
        int b = row2 / P_PAD; r = row2 % P_PAD;
        src = nfeats + ((size_t)b * 196 + r) * 128;
        dst = nfH + (size_t)row2 * 128;
    }
    if (r < 196) {
        float2 v = *(const float2*)(src + lane * 2);
        float ss = v.x * v.x + v.y * v.y;
        #pragma unroll
        for (int m = 1; m < 64; m <<= 1) ss += __shfl_xor(ss, m, 64);
        float rn = rsqrtf(ss);
        ushort2 o; o.x = f2h(v.x * rn); o.y = f2h(v.y * rn);
        *(ushort2*)(dst + lane * 2) = o;
    } else {
        *(unsigned int*)(dst + lane * 2) = 0u;   // zero pad rows
    }
}

// ---------------- kernel 2: LDS-staged A-panel, 4x4 output grid per wave ----
// One q-group: NQ q-tiles (16 cols each) of one b, full K=128 accumulation,
// then max-fold into runmax. MASKED only for the final tile (q=192..207).
template <int NQ, bool MASKED>
__device__ __forceinline__ void qgroup(
    const unsigned short* __restrict__ nb, int qt0, const f16x8* Apanel,
    int wave, int lr, int lg, float (&runmax)[4][4])
{
    f32x4 acc[4][NQ];
    #pragma unroll
    for (int i = 0; i < 4; ++i)
        #pragma unroll
        for (int n = 0; n < NQ; ++n) acc[i][n] = (f32x4){0.f, 0.f, 0.f, 0.f};

    f16x8 bA[NQ], bB[NQ];
    #pragma unroll
    for (int n = 0; n < NQ; ++n)
        bA[n] = *(const f16x8*)(nb + (size_t)(qt0 + n) * 2048);          // ks=0

    #pragma unroll
    for (int ks = 0; ks < 4; ++ks) {
        const f16x8* bc = (ks & 1) ? bB : bA;   // ks constant after unroll -> folds
        f16x8*       bn = (ks & 1) ? bA : bB;
        if (ks < 3) {
            #pragma unroll
            for (int n = 0; n < NQ; ++n)
                bn[n] = *(const f16x8*)(nb + (size_t)(qt0 + n) * 2048 + (ks + 1) * 32);
        }
        f16x8 af[4];
        #pragma unroll
        for (int i = 0; i < 4; ++i)
            if (i < 3 || wave == 0)
                af[i] = Apanel[(((wave + 4 * i) * 16 + lr) << 4) | ((ks * 4 + lg) ^ (lr & 7))];
        #pragma unroll
        for (int i = 0; i < 4; ++i)
            if (i < 3 || wave == 0) {
                #pragma unroll
                for (int n = 0; n < NQ; ++n)
                    asm("v_mfma_f32_16x16x32_f16 %0, %1, %2, %0"
                        : "+v"(acc[i][n]) : "v"(af[i]), "v"(bc[n]));
            }
    }
    asm volatile("s_nop 7\n\ts_nop 7");         // MFMA -> VALU hazard insurance
    #pragma unroll
    for (int i = 0; i < 4; ++i)
        if (i < 3 || wave == 0) {
            #pragma unroll
            for (int n = 0; n < NQ; ++n)
                #pragma unroll
                for (int r = 0; r < 4; ++r) {
                    float v = acc[i][n][r];
                    if (MASKED) v = (lr < 4) ? v : -3.0f;   // q=192+lr valid iff lr<4
                    runmax[i][r] = fmaxf(runmax[i][r], v);
                }
        }
}

__global__ __launch_bounds__(256, 1) void simmax_kernel(
    const unsigned short* __restrict__ fH, const unsigned short* __restrict__ nfH,
    const float* __restrict__ mask, float* __restrict__ sp, float* __restrict__ scores)
{
    int blk = blockIdx.x;
    int a = blk & 31, bg = blk >> 5;      // b-group-major: 32 consecutive blocks share 4 b-panels
    int tid = threadIdx.x, wave = tid >> 6, lane = tid & 63;
    int lr = lane & 15, lg = lane >> 4;

    __shared__ f16x8 Apanel[3328];        // [row 0..207][chunk 0..15], chunk col ^= row&7
    __shared__ unsigned smax_u[4];
    if (tid < 4) smax_u[tid] = 0u;

    // stage A-panel: coalesced global read, swizzled LDS write (2-way banks = free)
    const f16x8* fsrc = (const f16x8*)(fH + (size_t)a * P_PAD * 128);
    #pragma unroll
    for (int i = 0; i < 13; ++i) {
        int c = i * 256 + tid;
        int row = c >> 4, cc = c & 15;
        Apanel[(row << 4) | (cc ^ (row & 7))] = fsrc[c];
    }
    __syncthreads();

    for (int bi = 0; bi < 4; ++bi) {
        int b = bg * 4 + bi;
        const unsigned short* nb = nfH + (size_t)b * P_PAD * 128 + lr * 128 + lg * 8;

        float runmax[4][4];
        #pragma unroll
        for (int i = 0; i < 4; ++i)
            #pragma unroll
            for (int r = 0; r < 4; ++r) runmax[i][r] = -3.0f;

        for (int qg = 0; qg < 3; ++qg)
            qgroup<4, false>(nb, qg * 4, Apanel, wave, lr, lg, runmax);
        qgroup<1, true>(nb, 12, Apanel, wave, lr, lg, runmax);

        // reduce max across the 16 q-columns (lane bits 0..3), write sp + block max
        float blockmax = 0.0f;
        #pragma unroll
        for (int i = 0; i < 4; ++i) {
            if (i < 3 || wave == 0) {
                int mt = wave + 4 * i;
                #pragma unroll
                for (int r = 0; r < 4; ++r) {
                    float m = runmax[i][r];
                    m = fmaxf(m, __shfl_xor(m, 1, 64));
                    m = fmaxf(m, __shfl_xor(m, 2, 64));
                    m = fmaxf(m, __shfl_xor(m, 4, 64));
                    m = fmaxf(m, __shfl_xor(m, 8, 64));
                    if (lr == 0) {
                        int p = mt * 16 + lg * 4 + r;   // C/D: row = 4*(lane>>4)+reg
                        if (p < 196) {
                            float d = 0.5f * sqrtf(fmaxf(2.0f - 2.0f * m, 0.0f)) * mask[a * 196 + p];
                            sp[((size_t)a * 196 + p) * 64 + b] = d;   // [a][p][b]
                            blockmax = fmaxf(blockmax, d);
                        }
                    }
                }
            }
        }
        atomicMax(&smax_u[bi], __float_as_uint(blockmax));   // all values >= 0
    }
    __syncthreads();
    if (tid < 4) scores[a * 64 + bg * 4 + tid] = __uint_as_float(smax_u[tid]);
}

// ---------------- kernel 3: patch mean over b + scores mean ----
__global__ __launch_bounds__(256) void patchmean_kernel(
    const float* __restrict__ sp, const float* __restrict__ scores,
    float* __restrict__ patch, float* __restrict__ out)
{
    int a = blockIdx.x, tid = threadIdx.x;
    if (tid < 196) {
        const f32x4* v = (const f32x4*)(sp + ((size_t)a * 196 + tid) * 64);
        float s = 0.0f;
        #pragma unroll
        for (int j = 0; j < 16; ++j) { f32x4 x = v[j]; s += x[0] + x[1] + x[2] + x[3]; }
        patch[a * 196 + tid] = s * (1.0f / 64.0f);
    }
    if (tid >= 192 && tid < 256) {         // wave 3: scores mean
        int l = tid - 192;
        float s = scores[a * 64 + l];
        #pragma unroll
        for (int m = 1; m < 64; m <<= 1) s += __shfl_xor(s, m, 64);
        if (l == 0) out[a] = s * (1.0f / 64.0f);
    }
}

// ---------------- kernel 4: bilinear 14x14 -> 224x224, 8-row bands ----
__global__ __launch_bounds__(256) void upsample_kernel(
    const float* __restrict__ patch, float* __restrict__ out)
{
    int bid = blockIdx.x;
    int a = bid / 28, band = bid % 28;
    __shared__ float pt[196];
    if (threadIdx.x < 196) pt[threadIdx.x] = patch[a * 196 + threadIdx.x];
    __syncthreads();

    float* op = out + 32 + (size_t)a * 50176 + band * 8 * 224;
    for (int t = threadIdx.x; t < 8 * 224; t += 256) {
        int h = band * 8 + (t / 224), w = t % 224;
        float sh = fmaxf((h + 0.5f) * 0.0625f - 0.5f, 0.0f);   // 14/224 = 1/16
        float sw = fmaxf((w + 0.5f) * 0.0625f - 0.5f, 0.0f);
        int h0 = (int)sh, w0 = (int)sw;
        int h1 = min(h0 + 1, 13), w1 = min(w0 + 1, 13);
        float fh = sh - (float)h0, fw = sw - (float)w0;
        float v00 = pt[h0 * 14 + w0], v01 = pt[h0 * 14 + w1];
        float v10 = pt[h1 * 14 + w0], v11 = pt[h1 * 14 + w1];
        op[t] = (1.0f - fh) * ((1.0f - fw) * v00 + fw * v01)
              +         fh  * ((1.0f - fw) * v10 + fw * v11);
    }
}

extern "C" void kernel_launch(void* const* d_in, const int* in_sizes, int n_in,
                              void* d_out, int out_size, void* d_ws, size_t ws_size,
                              hipStream_t stream) {
    const float* feats  = (const float*)d_in[0];   // [32,196,128]
    const float* nfeats = (const float*)d_in[1];   // [64,196,128]
    const float* mask   = (const float*)d_in[2];   // [32,196]
    float* out = (float*)d_out;                    // 32 + 32*224*224

    char* w = (char*)d_ws;
    unsigned short* fH  = (unsigned short*)(w);            // 32*208*128 f16 = 1,703,936 B
    unsigned short* nfH = (unsigned short*)(w + 1703936);  // 64*208*128 f16 = 3,407,872 B
    float* sp     = (float*)(w + 5111808);                 // 32*196*64 f32  = 1,605,632 B
    float* scores = (float*)(w + 6717440);                 // 2048 f32
    float* patch  = (float*)(w + 6725632);                 // 32*196 f32

    norm_kernel<<<4992, 256, 0, stream>>>(feats, nfeats, fH, nfH);
    simmax_kernel<<<512, 256, 0, stream>>>(fH, nfH, mask, sp, scores);
    patchmean_kernel<<<32, 256, 0, stream>>>(sp, scores, patch, out);
    upsample_kernel<<<896, 256, 0, stream>>>(patch, out);
}